// Round 3
// baseline (29.183 us; speedup 1.0000x reference)
//
#include <hip/hip_runtime.h>

// BilinearSparseRouting — collapsed form (dots = softmax(const) = 1/32 exactly):
//   S[b] (4x4) = sum_j cp_mat[b,j] @ wc[j]
//   out[b,i]   = (1/32) * S[b] @ wn[i]
//
// Single fused kernel, 256 blocks (1/CU) x 1024 threads.
// R3 changes vs R2:
//  - explicit 2-deep software pipeline (two named reg buffers) so each
//    FMA block runs with the next iteration's 8 float4 loads in flight
//    (1024-thr blocks cap VGPR at 128/wave; 2x(4+4) f32x4 buffers = 64 VGPR fits)
//  - nontemporal loads for the streaming cp operand (no reuse, keep L2 for wc)

#define BATCH 256
#define NIN   4096
#define NOUT  32

constexpr int THREADS = 1024;
constexpr int JPT     = NIN / THREADS;  // 4 j per thread

typedef __attribute__((ext_vector_type(4))) float f32x4;

__device__ __forceinline__ void mm4(const f32x4 a[4], const f32x4 w[4],
                                    float acc[16]) {
#pragma unroll
    for (int r = 0; r < 4; ++r)
#pragma unroll
        for (int c = 0; c < 4; ++c)
#pragma unroll
            for (int k = 0; k < 4; ++k)
                acc[r * 4 + c] += a[r][k] * w[k][c];
}

__global__ __launch_bounds__(THREADS)
void caps_fused(const float* __restrict__ cp,
                const float* __restrict__ wc,
                const float* __restrict__ wn,
                float* __restrict__ out) {
    const int b    = blockIdx.x;
    const int t    = threadIdx.x;
    const int lane = t & 63;
    const int wave = t >> 6;            // 16 waves

    float acc[16];
#pragma unroll
    for (int e = 0; e < 16; ++e) acc[e] = 0.f;

    // per-thread base: j = i*THREADS + t; 16 floats per j = 4 f32x4
    const f32x4* cp4 = (const f32x4*)(cp + ((size_t)b * NIN + t) * 16);
    const f32x4* wc4 = (const f32x4*)(wc + (size_t)t * 16);
    constexpr int STRIDE = THREADS * 4;   // f32x4 per j-iter step

    f32x4 A[4], W[4], Bf[4], X[4];

#define LOADI(P, Q, i)                                                   \
    do {                                                                 \
        _Pragma("unroll")                                                \
        for (int v = 0; v < 4; ++v) {                                    \
            P[v] = __builtin_nontemporal_load(cp4 + (i) * STRIDE + v);   \
            Q[v] = wc4[(i) * STRIDE + v];                                \
        }                                                                \
    } while (0)

    static_assert(JPT == 4, "pipeline written for JPT==4");
    LOADI(A, W, 0);
    LOADI(Bf, X, 1);
    mm4(A, W, acc);
    LOADI(A, W, 2);
    mm4(Bf, X, acc);
    LOADI(Bf, X, 3);
    mm4(A, W, acc);
    mm4(Bf, X, acc);
#undef LOADI

    // Halving butterfly reduce across the wave (exchange half each step).
    // After masks 1,2,4,8 lane l holds element e(l) = bit-reversed low nibble.
    {
        const bool hi1 = lane & 1;
#pragma unroll
        for (int e = 0; e < 8; ++e) {
            float a0 = acc[e], a1 = acc[e + 8];
            float send = hi1 ? a0 : a1;
            float keep = hi1 ? a1 : a0;
            acc[e] = keep + __shfl_xor(send, 1);
        }
        const bool hi2 = lane & 2;
#pragma unroll
        for (int e = 0; e < 4; ++e) {
            float a0 = acc[e], a1 = acc[e + 4];
            float send = hi2 ? a0 : a1;
            float keep = hi2 ? a1 : a0;
            acc[e] = keep + __shfl_xor(send, 2);
        }
        const bool hi4 = lane & 4;
#pragma unroll
        for (int e = 0; e < 2; ++e) {
            float a0 = acc[e], a1 = acc[e + 2];
            float send = hi4 ? a0 : a1;
            float keep = hi4 ? a1 : a0;
            acc[e] = keep + __shfl_xor(send, 4);
        }
        {
            const bool hi8 = lane & 8;
            float a0 = acc[0], a1 = acc[1];
            float send = hi8 ? a0 : a1;
            float keep = hi8 ? a1 : a0;
            acc[0] = keep + __shfl_xor(send, 8);
        }
        acc[0] += __shfl_xor(acc[0], 16);
        acc[0] += __shfl_xor(acc[0], 32);
    }

    __shared__ float red[16][16];   // [wave][element]
    __shared__ float S[16];
    if (lane < 16) {
        const int e = ((lane & 1) ? 8 : 0) | ((lane & 2) ? 4 : 0) |
                      ((lane & 4) ? 2 : 0) | ((lane & 8) ? 1 : 0);
        red[wave][e] = acc[0];
    }
    __syncthreads();

    if (t < 16) {
        float v = 0.f;
#pragma unroll
        for (int w2 = 0; w2 < 16; ++w2) v += red[w2][t];
        S[t] = v * (1.0f / 32.0f);
    }
    __syncthreads();

    // Epilogue: out[b,i,r,0..3] = S[r,:] @ wn[i][:,0..3], 128 threads x float4
    if (t < NOUT * 4) {
        const int i = t >> 2;
        const int r = t & 3;
        const f32x4* wn4 = (const f32x4*)(wn + i * 16);
        f32x4 w0 = wn4[0], w1 = wn4[1], w2 = wn4[2], w3 = wn4[3];
        float s0 = S[r * 4 + 0], s1 = S[r * 4 + 1], s2 = S[r * 4 + 2], s3 = S[r * 4 + 3];
        f32x4 o;
        o[0] = s0 * w0[0] + s1 * w1[0] + s2 * w2[0] + s3 * w3[0];
        o[1] = s0 * w0[1] + s1 * w1[1] + s2 * w2[1] + s3 * w3[1];
        o[2] = s0 * w0[2] + s1 * w1[2] + s2 * w2[2] + s3 * w3[2];
        o[3] = s0 * w0[3] + s1 * w1[3] + s2 * w2[3] + s3 * w3[3];
        ((f32x4*)(out + (size_t)b * NOUT * 16))[t] = o;
    }
}

extern "C" void kernel_launch(void* const* d_in, const int* in_sizes, int n_in,
                              void* d_out, int out_size, void* d_ws, size_t ws_size,
                              hipStream_t stream) {
    const float* cp = (const float*)d_in[0];   // (256,4096,16)
    const float* wc = (const float*)d_in[1];   // (1,1,4096,4,4)
    const float* wn = (const float*)d_in[2];   // (32,4,4)
    float* out = (float*)d_out;                // (256,1,1,32,16)

    caps_fused<<<BATCH, THREADS, 0, stream>>>(cp, wc, wn, out);
}

// Round 4
// 19.494 us; speedup vs baseline: 1.4970x; 1.4970x over previous
//
#include <hip/hip_runtime.h>

// BilinearSparseRouting — collapsed form (dots = softmax(const) = 1/32 exactly):
//   S[b] (4x4) = sum_j cp_mat[b,j] @ wc[j]
//   out[b,i]   = (1/32) * S[b] @ wn[i]
//
// R4: 256 blocks x 512 threads (1 block/CU, 8 waves/CU), JPT=8.
// Rationale: 512-thr blocks lift the VGPR cap 128 -> 256, letting the
// compiler hoist many more of the unrolled loads per wave (ILP for latency
// hiding); R3's nontemporal + manual pipeline are reverted (regression).

#define BATCH 256
#define NIN   4096
#define NOUT  32

constexpr int THREADS = 512;
constexpr int JPT     = NIN / THREADS;  // 8 j per thread
constexpr int WAVES   = THREADS / 64;   // 8

typedef __attribute__((ext_vector_type(4))) float f32x4;

__global__ __launch_bounds__(THREADS)
void caps_fused(const float* __restrict__ cp,
                const float* __restrict__ wc,
                const float* __restrict__ wn,
                float* __restrict__ out) {
    const int b    = blockIdx.x;
    const int t    = threadIdx.x;
    const int lane = t & 63;
    const int wave = t >> 6;

    float acc[16];
#pragma unroll
    for (int e = 0; e < 16; ++e) acc[e] = 0.f;

    // per-thread: j = it*THREADS + t, 4 consecutive f32x4 per j
    const f32x4* cp4 = (const f32x4*)(cp + ((size_t)b * NIN + t) * 16);
    const f32x4* wc4 = (const f32x4*)(wc + (size_t)t * 16);
    constexpr int STRIDE = THREADS * 4;   // f32x4 step per j-iter

#pragma unroll
    for (int it = 0; it < JPT; ++it) {
        f32x4 a[4], w[4];
#pragma unroll
        for (int v = 0; v < 4; ++v) {
            a[v] = cp4[it * STRIDE + v];
            w[v] = wc4[it * STRIDE + v];
        }
#pragma unroll
        for (int r = 0; r < 4; ++r)
#pragma unroll
            for (int c = 0; c < 4; ++c)
#pragma unroll
                for (int k = 0; k < 4; ++k)
                    acc[r * 4 + c] += a[r][k] * w[k][c];
    }

    // Halving butterfly reduce across the wave (exchange half each step).
    // After masks 1,2,4,8 lane l holds element e(l) = bit-reversed low nibble.
    {
        const bool hi1 = lane & 1;
#pragma unroll
        for (int e = 0; e < 8; ++e) {
            float a0 = acc[e], a1 = acc[e + 8];
            float send = hi1 ? a0 : a1;
            float keep = hi1 ? a1 : a0;
            acc[e] = keep + __shfl_xor(send, 1);
        }
        const bool hi2 = lane & 2;
#pragma unroll
        for (int e = 0; e < 4; ++e) {
            float a0 = acc[e], a1 = acc[e + 4];
            float send = hi2 ? a0 : a1;
            float keep = hi2 ? a1 : a0;
            acc[e] = keep + __shfl_xor(send, 2);
        }
        const bool hi4 = lane & 4;
#pragma unroll
        for (int e = 0; e < 2; ++e) {
            float a0 = acc[e], a1 = acc[e + 2];
            float send = hi4 ? a0 : a1;
            float keep = hi4 ? a1 : a0;
            acc[e] = keep + __shfl_xor(send, 4);
        }
        {
            const bool hi8 = lane & 8;
            float a0 = acc[0], a1 = acc[1];
            float send = hi8 ? a0 : a1;
            float keep = hi8 ? a1 : a0;
            acc[0] = keep + __shfl_xor(send, 8);
        }
        acc[0] += __shfl_xor(acc[0], 16);
        acc[0] += __shfl_xor(acc[0], 32);
    }

    __shared__ float red[WAVES][16];
    __shared__ float S[16];
    if (lane < 16) {
        const int e = ((lane & 1) ? 8 : 0) | ((lane & 2) ? 4 : 0) |
                      ((lane & 4) ? 2 : 0) | ((lane & 8) ? 1 : 0);
        red[wave][e] = acc[0];
    }
    __syncthreads();

    if (t < 16) {
        float v = 0.f;
#pragma unroll
        for (int w2 = 0; w2 < WAVES; ++w2) v += red[w2][t];
        S[t] = v * (1.0f / 32.0f);
    }
    __syncthreads();

    // Epilogue: out[b,i,r,0..3] = S[r,:] @ wn[i][:,0..3], 128 threads x f32x4
    if (t < NOUT * 4) {
        const int i = t >> 2;
        const int r = t & 3;
        const f32x4* wn4 = (const f32x4*)(wn + i * 16);
        f32x4 w0 = wn4[0], w1 = wn4[1], w2 = wn4[2], w3 = wn4[3];
        float s0 = S[r * 4 + 0], s1 = S[r * 4 + 1], s2 = S[r * 4 + 2], s3 = S[r * 4 + 3];
        f32x4 o;
        o[0] = s0 * w0[0] + s1 * w1[0] + s2 * w2[0] + s3 * w3[0];
        o[1] = s0 * w0[1] + s1 * w1[1] + s2 * w2[1] + s3 * w3[1];
        o[2] = s0 * w0[2] + s1 * w1[2] + s2 * w2[2] + s3 * w3[2];
        o[3] = s0 * w0[3] + s1 * w1[3] + s2 * w2[3] + s3 * w3[3];
        ((f32x4*)(out + (size_t)b * NOUT * 16))[t] = o;
    }
}

extern "C" void kernel_launch(void* const* d_in, const int* in_sizes, int n_in,
                              void* d_out, int out_size, void* d_ws, size_t ws_size,
                              hipStream_t stream) {
    const float* cp = (const float*)d_in[0];   // (256,4096,16)
    const float* wc = (const float*)d_in[1];   // (1,1,4096,4,4)
    const float* wn = (const float*)d_in[2];   // (32,4,4)
    float* out = (float*)d_out;                // (256,1,1,32,16)

    caps_fused<<<BATCH, THREADS, 0, stream>>>(cp, wc, wn, out);
}

// Round 5
// 17.781 us; speedup vs baseline: 1.6412x; 1.0963x over previous
//
#include <hip/hip_runtime.h>

// BilinearSparseRouting — collapsed form (dots = softmax(const) = 1/32 exactly):
//   S[b] (4x4) = sum_j cp_mat[b,j] @ wc[j]
//   out[b,i]   = (1/32) * S[b] @ wn[i]
//
// R5: instruction-level coalescing. Loads use p = it*4096 + v*1024 + t so each
// global_load_dwordx4 is lane-contiguous (1 KiB/instr) instead of 64B-strided.
// Thread t holds ROW r=t&3 of matrix j=p>>2; a quad holds rows 0..3 of the
// same j for cp AND wc. W rows are shared quad-internally with static
// ds_swizzle quad-broadcasts (no extra global traffic, no LDS staging).
// Each thread accumulates only row r of S (4 floats).

#define BATCH 256
#define NIN   4096
#define NOUT  32

constexpr int THREADS = 1024;
constexpr int VPT     = 4;                      // f32x4 per thread per iter
constexpr int POS     = NIN * 4;                // 16384 f32x4 positions / batch
constexpr int ITERS   = POS / (THREADS * VPT);  // 4
constexpr int WAVES   = THREADS / 64;           // 16

typedef __attribute__((ext_vector_type(4))) float f32x4;

template<int K>
__device__ __forceinline__ f32x4 quad_bcast(f32x4 x) {
    // QuadMode ds_swizzle: lane reads (lane & ~3) | K  -> broadcast slot K
    constexpr int imm = 0x8000 | (0x55 * K);
    f32x4 r;
#pragma unroll
    for (int d = 0; d < 4; ++d)
        r[d] = __int_as_float(
            __builtin_amdgcn_ds_swizzle(__float_as_int(x[d]), imm));
    return r;
}

__global__ __launch_bounds__(THREADS)
void caps_fused(const float* __restrict__ cp,
                const float* __restrict__ wc,
                const float* __restrict__ wn,
                float* __restrict__ out) {
    const int b    = blockIdx.x;
    const int t    = threadIdx.x;
    const int lane = t & 63;
    const int wave = t >> 6;

    const f32x4* cp4 = (const f32x4*)cp + (size_t)b * POS;
    const f32x4* wc4 = (const f32x4*)wc;

    f32x4 acc = {0.f, 0.f, 0.f, 0.f};   // row r=t&3 of S, partial

#pragma unroll
    for (int it = 0; it < ITERS; ++it) {
        f32x4 a[VPT], w[VPT];
#pragma unroll
        for (int v = 0; v < VPT; ++v) {
            const int p = it * (THREADS * VPT) + v * THREADS + t;
            a[v] = cp4[p];        // A_j row r   (lane-contiguous load)
            w[v] = wc4[p];        // W_j row r   (lane-contiguous load)
        }
#pragma unroll
        for (int v = 0; v < VPT; ++v) {
            const f32x4 w0 = quad_bcast<0>(w[v]);
            const f32x4 w1 = quad_bcast<1>(w[v]);
            const f32x4 w2 = quad_bcast<2>(w[v]);
            const f32x4 w3 = quad_bcast<3>(w[v]);
            // acc[c] += sum_k a[k] * W[k][c]
            acc += a[v][0] * w0;
            acc += a[v][1] * w1;
            acc += a[v][2] * w2;
            acc += a[v][3] * w3;
        }
    }

    // Sum across lanes with equal (lane&3): butterfly over masks 4,8,16,32.
#pragma unroll
    for (int m = 4; m <= 32; m <<= 1) {
#pragma unroll
        for (int c = 0; c < 4; ++c)
            acc[c] += __shfl_xor(acc[c], m, 64);
    }

    __shared__ f32x4 red[WAVES][4];
    __shared__ float S[16];
    if (lane < 4) red[wave][lane] = acc;   // lane == row r
    __syncthreads();

    if (t < 16) {                           // t = r*4 + c
        float v = 0.f;
#pragma unroll
        for (int w2 = 0; w2 < WAVES; ++w2) v += red[w2][t >> 2][t & 3];
        S[t] = v * (1.0f / 32.0f);
    }
    __syncthreads();

    // Epilogue: out[b,i,r,0..3] = S[r,:] @ wn[i][:,0..3], 128 threads x f32x4
    if (t < NOUT * 4) {
        const int i = t >> 2;
        const int r = t & 3;
        const f32x4* wn4 = (const f32x4*)(wn + i * 16);
        const f32x4 w0 = wn4[0], w1 = wn4[1], w2 = wn4[2], w3 = wn4[3];
        const float s0 = S[r * 4 + 0], s1 = S[r * 4 + 1];
        const float s2 = S[r * 4 + 2], s3 = S[r * 4 + 3];
        f32x4 o;
        o[0] = s0 * w0[0] + s1 * w1[0] + s2 * w2[0] + s3 * w3[0];
        o[1] = s0 * w0[1] + s1 * w1[1] + s2 * w2[1] + s3 * w3[1];
        o[2] = s0 * w0[2] + s1 * w1[2] + s2 * w2[2] + s3 * w3[2];
        o[3] = s0 * w0[3] + s1 * w1[3] + s2 * w2[3] + s3 * w3[3];
        ((f32x4*)(out + (size_t)b * NOUT * 16))[t] = o;
    }
}

extern "C" void kernel_launch(void* const* d_in, const int* in_sizes, int n_in,
                              void* d_out, int out_size, void* d_ws, size_t ws_size,
                              hipStream_t stream) {
    const float* cp = (const float*)d_in[0];   // (256,4096,16)
    const float* wc = (const float*)d_in[1];   // (1,1,4096,4,4)
    const float* wn = (const float*)d_in[2];   // (32,4,4)
    float* out = (float*)d_out;                // (256,1,1,32,16)

    caps_fused<<<BATCH, THREADS, 0, stream>>>(cp, wc, wn, out);
}